// Round 16
// baseline (1565.149 us; speedup 1.0000x reference)
//
#include <hip/hip_runtime.h>
#include <hip/hip_bf16.h>
#include <stdint.h>

typedef float  f32x4  __attribute__((ext_vector_type(4)));
typedef __bf16 bf16x8 __attribute__((ext_vector_type(8)));
typedef unsigned short u16x8 __attribute__((ext_vector_type(8)));

__device__ __forceinline__ unsigned short f2bf_rne(float f) {
    uint32_t x = __float_as_uint(f);
    uint32_t r = x + 0x7FFFu + ((x >> 16) & 1u);
    return (unsigned short)(r >> 16);
}

__global__ __launch_bounds__(256) void cvt_f32_bf16(const float* __restrict__ src,
                                                    unsigned short* __restrict__ dst,
                                                    long n) {
    long i0 = ((long)blockIdx.x * blockDim.x + threadIdx.x) * 8;
    long stride = (long)gridDim.x * blockDim.x * 8;
    for (long j = i0; j + 8 <= n; j += stride) {
        float4 v0 = *(const float4*)(src + j);
        float4 v1 = *(const float4*)(src + j + 4);
        u16x8 o;
        o[0] = f2bf_rne(v0.x); o[1] = f2bf_rne(v0.y);
        o[2] = f2bf_rne(v0.z); o[3] = f2bf_rne(v0.w);
        o[4] = f2bf_rne(v1.x); o[5] = f2bf_rne(v1.y);
        o[6] = f2bf_rne(v1.z); o[7] = f2bf_rne(v1.w);
        *(u16x8*)(dst + j) = o;
    }
}

#define GLL(SRC, DST) __builtin_amdgcn_global_load_lds(                      \
    (const __attribute__((address_space(1))) void*)(SRC),                    \
    (__attribute__((address_space(3))) void*)(DST), 16, 0, 0)
#define BARRIER() asm volatile("s_barrier" ::: "memory")
#define WAITV(N) asm volatile("s_waitcnt vmcnt(" #N ")" ::: "memory")
#define WAITL(N) do { asm volatile("s_waitcnt lgkmcnt(" #N ")" ::: "memory"); \
                      __builtin_amdgcn_sched_barrier(0); } while (0)

// 128x128 tile, BK=64, 4 waves (2Mx2N, 64x64 out/wave), 64KB dbuf LDS ->
// TWO blocks per CU. Hypothesis: independent blocks' phases drift, so one
// block's DS burst overlaps the other's MFMA burst (lockstep serialization
// is what pins the 256-square structure at 49%). r8 phase discipline:
// reads -> barrier -> WAITL(0)+sched_barrier -> MFMA -> barrier -> stage ->
// counted vmcnt -> barrier. Same verified 0-conflict swizzled layout
// (row stride 128B identical to r2). Ledger: 8 GLL/tile; prologue 16 out,
// WAITV(8) drains t0; per tile STAGE(t+2) -> 16 out -> WAITV(8) drains t+1.
// Regs: acc 64 + af 32 + bq 32 + addr ~25 -> no spill at 2 waves/SIMD.
__global__ __launch_bounds__(256, 2) void gemm128_db(
    const unsigned short* __restrict__ A, const unsigned short* __restrict__ B,
    const float* __restrict__ bias, float* __restrict__ C,
    int M, int N, int K) {
    __shared__ __align__(16) char lds[65536];   // buf(32KB): A[128][64] @0, B @16384
    const int tid  = threadIdx.x;
    const int lane = tid & 63;
    const int wave = tid >> 6;       // 0..3
    const int wr  = wave >> 1;       // 0..1
    const int wc  = wave & 1;        // 0..1
    const int l15 = lane & 15;
    const int l4  = lane >> 4;

    // supertile: 8m x 8n = 64 wgs per XCD batch (2 blocks/CU x 32 CU);
    // per-K-step L2 working set = 8*16KB + 8*16KB = 256KB << 4MiB.
    const int nwg = gridDim.x;
    const int Mt  = M >> 7;
    const int Nt  = N >> 7;
    const int bid = blockIdx.x;
    int tm, tn;
    if ((Mt & 7) == 0 && (Nt & 7) == 0 && (nwg & 63) == 0) {
        const int nst = nwg >> 6;    // supertiles (64 wgs each)
        const int q2  = nst >> 3;    // supertiles per XCD
        const int xc  = bid & 7;
        const int oo  = bid >> 3;
        const int idx = oo & 63;     // position in supertile
        const int h   = oo >> 6;     // supertile index within XCD
        const int st  = xc * q2 + h;
        const int Mst = Mt >> 3;
        const int stm = st % Mst;
        const int stn = st / Mst;
        tm = stm * 8 + (idx & 7);
        tn = stn * 8 + (idx >> 3);
    } else {
        int qq = nwg >> 3, rr = nwg & 7, xc = bid & 7, oo = bid >> 3;
        int wg = (xc < rr ? xc * (qq + 1) : rr * (qq + 1) + (xc - rr) * qq) + oo;
        tm = wg / Nt; tn = wg % Nt;
    }
    const long m0 = (long)tm << 7;
    const long n0 = (long)tn << 7;

    const int colSw = ((tid & 7) ^ ((tid >> 3) & 7)) << 3;  // inverse-swizzled src col
    const int row8  = tid >> 3;      // 0..31
    const long Kl = K;

    // stage one K-tile (A 16KB + B 16KB): 8 GLL/thread, linear dst + swizzled src.
    // dst elem = tid*8 + j*2048 -> row = row8 + j*32 (row&7 == (tid>>3)&7 for all j).
    auto STAGE = [&](int buf, int t) {
        char* dstA = lds + (buf << 15) + tid * 16;
        char* dstB = dstA + 16384;
        long col = (long)t * 64 + colSw;
#pragma unroll
        for (int j = 0; j < 4; ++j)
            GLL(A + (m0 + j * 32 + row8) * Kl + col, dstA + j * 4096);
#pragma unroll
        for (int j = 0; j < 4; ++j)
            GLL(B + (n0 + j * 32 + row8) * Kl + col, dstB + j * 4096);
    };
    auto LDA = [&](int buf, int m, int kk) -> bf16x8 {
        int off = (((wr * 64 + m * 16 + l15) * 64 + kk * 32 + l4 * 8) * 2) ^ ((l15 & 7) << 4);
        return *(const bf16x8*)(lds + (buf << 15) + off);
    };
    auto LDB = [&](int buf, int n, int kk) -> bf16x8 {
        int off = (((wc * 64 + n * 16 + l15) * 64 + kk * 32 + l4 * 8) * 2) ^ ((l15 & 7) << 4);
        return *(const bf16x8*)(lds + (buf << 15) + 16384 + off);
    };

    f32x4 acc[4][4] = {};            // 64 regs
    bf16x8 af[4][2], bq[4][2];       // 64 regs

    const int NT = K >> 6;

    // prologue: stage tiles 0,1 (8 GLL each); drain tile 0, keep tile 1 in flight
    STAGE(0, 0); STAGE(1, 1);
    WAITV(8);
    BARRIER();

    for (int t = 0; t < NT; ++t) {
        const int c = t & 1;
        // reads for this tile (16 ds_read_b128)
#pragma unroll
        for (int m = 0; m < 4; ++m) { af[m][0] = LDA(c, m, 0); af[m][1] = LDA(c, m, 1); }
#pragma unroll
        for (int n = 0; n < 4; ++n) { bq[n][0] = LDB(c, n, 0); bq[n][1] = LDB(c, n, 1); }
        BARRIER(); WAITL(0);
        __builtin_amdgcn_s_setprio(1);
#pragma unroll
        for (int kk = 0; kk < 2; ++kk)
#pragma unroll
            for (int m = 0; m < 4; ++m)
#pragma unroll
                for (int n = 0; n < 4; ++n)
                    acc[m][n] = __builtin_amdgcn_mfma_f32_16x16x32_bf16(
                        af[m][kk], bq[n][kk], acc[m][n], 0, 0, 0);
        __builtin_amdgcn_s_setprio(0);
        BARRIER();                   // all waves done reading buf c -> re-stage safe
        if (t + 2 < NT) {
            STAGE(c, t + 2);         // 8 GLL -> 16 outstanding
            WAITV(8);                // drain tile t+1's 8, keep t+2's 8 in flight
            BARRIER();               // tile t+1 visible
        } else if (t + 1 < NT) {
            WAITV(0);                // drain last tile
            BARRIER();
        }
    }

    // epilogue: D mapping col = l15, row = l4*4 + j within each 16x16 fragment
#pragma unroll
    for (int n = 0; n < 4; ++n) {
        const long col = n0 + wc * 64 + n * 16 + l15;
        const float bv = bias[col];
#pragma unroll
        for (int m = 0; m < 4; ++m) {
            float* Cp = C + (m0 + wr * 64 + m * 16 + l4 * 4) * (long)N + col;
#pragma unroll
            for (int j = 0; j < 4; ++j)
                Cp[(long)j * N] = acc[m][n][j] + bv;
        }
    }
}

// fallback: m97-structure 128x128 (verified round 1)
__global__ __launch_bounds__(256) void gemm_bt_bias(const unsigned short* __restrict__ A,
                                                    const unsigned short* __restrict__ B,
                                                    const float* __restrict__ bias,
                                                    float* __restrict__ C,
                                                    int M, int N, int K) {
    __shared__ unsigned short lds_a[128 * 32];
    __shared__ unsigned short lds_b[128 * 32];
    const int tid  = threadIdx.x;
    const int lane = tid & 63;
    const int wave = tid >> 6;
    const int wrr = wave >> 1, wcc = wave & 1;
    const int l15 = lane & 15, l4 = lane >> 4;
    const int nTilesN = N / 128;
    const long m0 = (long)(blockIdx.x / nTilesN) * 128;
    const long n0 = (long)(blockIdx.x % nTilesN) * 128;
    f32x4 acc[4][4] = {};
    const unsigned short* aSrc = A + (m0 + (tid >> 2)) * (long)K + ((tid & 3) * 8);
    const unsigned short* bSrc = B + (n0 + (tid >> 2)) * (long)K + ((tid & 3) * 8);
    char* aDst = (char*)lds_a + tid * 16;
    char* bDst = (char*)lds_b + tid * 16;
    for (int k0 = 0; k0 < K; k0 += 32) {
#pragma unroll
        for (int i = 0; i < 2; i++) {
            GLL(aSrc + (long)i * 64 * K + k0, aDst + i * 4096);
            GLL(bSrc + (long)i * 64 * K + k0, bDst + i * 4096);
        }
        __syncthreads();
        bf16x8 afr[4], bfr[4];
#pragma unroll
        for (int r = 0; r < 4; r++)
            afr[r] = *(const bf16x8*)&lds_a[(wrr * 64 + r * 16 + l15) * 32 + l4 * 8];
#pragma unroll
        for (int c = 0; c < 4; c++)
            bfr[c] = *(const bf16x8*)&lds_b[(wcc * 64 + c * 16 + l15) * 32 + l4 * 8];
#pragma unroll
        for (int r = 0; r < 4; r++)
#pragma unroll
            for (int c = 0; c < 4; c++)
                acc[r][c] = __builtin_amdgcn_mfma_f32_16x16x32_bf16(afr[r], bfr[c], acc[r][c], 0, 0, 0);
        __syncthreads();
    }
#pragma unroll
    for (int c = 0; c < 4; c++) {
        const long n = n0 + wcc * 64 + c * 16 + l15;
        const float bv = bias[n];
#pragma unroll
        for (int r = 0; r < 4; r++) {
            const long m = m0 + wrr * 64 + r * 16 + l4 * 4;
            float* Cp = C + m * (long)N + n;
#pragma unroll
            for (int j = 0; j < 4; j++)
                Cp[(long)j * N] = acc[r][c][j] + bv;
        }
    }
}

extern "C" void kernel_launch(void* const* d_in, const int* in_sizes, int n_in,
                              void* d_out, int out_size, void* d_ws, size_t ws_size,
                              hipStream_t stream) {
    const float* x    = (const float*)d_in[0];
    const float* w    = (const float*)d_in[1];
    const float* bias = (const float*)d_in[2];
    float* out = (float*)d_out;

    const long Nn = in_sizes[2];             // OUT = 4096
    const long Kk = (long)in_sizes[1] / Nn;  // IN  = 16384
    const long Mm = (long)in_sizes[0] / Kk;  // B*S = 8192

    unsigned short* aB = (unsigned short*)d_ws;
    unsigned short* bB = aB + Mm * Kk;
    cvt_f32_bf16<<<2048, 256, 0, stream>>>(x, aB, Mm * Kk);
    cvt_f32_bf16<<<2048, 256, 0, stream>>>(w, bB, Nn * Kk);

    if ((Mm & 127) == 0 && (Nn & 127) == 0 && (Kk & 63) == 0 && Kk >= 192) {
        const int grid = (int)((Mm >> 7) * (Nn >> 7));
        gemm128_db<<<grid, 256, 0, stream>>>(aB, bB, bias, out, (int)Mm, (int)Nn, (int)Kk);
    } else {
        const int grid = (int)((Mm / 128) * (Nn / 128));
        gemm_bt_bias<<<grid, 256, 0, stream>>>(aB, bB, bias, out, (int)Mm, (int)Nn, (int)Kk);
    }
}

// Round 17
// 1367.734 us; speedup vs baseline: 1.1443x; 1.1443x over previous
//
#include <hip/hip_runtime.h>
#include <hip/hip_bf16.h>
#include <stdint.h>

typedef float  f32x4  __attribute__((ext_vector_type(4)));
typedef __bf16 bf16x8 __attribute__((ext_vector_type(8)));
typedef unsigned short u16x8 __attribute__((ext_vector_type(8)));

__device__ __forceinline__ unsigned short f2bf_rne(float f) {
    uint32_t x = __float_as_uint(f);
    uint32_t r = x + 0x7FFFu + ((x >> 16) & 1u);
    return (unsigned short)(r >> 16);
}

__global__ __launch_bounds__(256) void cvt_f32_bf16(const float* __restrict__ src,
                                                    unsigned short* __restrict__ dst,
                                                    long n) {
    long i0 = ((long)blockIdx.x * blockDim.x + threadIdx.x) * 8;
    long stride = (long)gridDim.x * blockDim.x * 8;
    for (long j = i0; j + 8 <= n; j += stride) {
        float4 v0 = *(const float4*)(src + j);
        float4 v1 = *(const float4*)(src + j + 4);
        u16x8 o;
        o[0] = f2bf_rne(v0.x); o[1] = f2bf_rne(v0.y);
        o[2] = f2bf_rne(v0.z); o[3] = f2bf_rne(v0.w);
        o[4] = f2bf_rne(v1.x); o[5] = f2bf_rne(v1.y);
        o[6] = f2bf_rne(v1.z); o[7] = f2bf_rne(v1.w);
        *(u16x8*)(dst + j) = o;
    }
}

#define GLL(SRC, DST) __builtin_amdgcn_global_load_lds(                      \
    (const __attribute__((address_space(1))) void*)(SRC),                    \
    (__attribute__((address_space(3))) void*)(DST), 16, 0, 0)
#define BARRIER() asm volatile("s_barrier" ::: "memory")
#define WAITV(N) asm volatile("s_waitcnt vmcnt(" #N ")" ::: "memory")
#define WAITL(N) do { asm volatile("s_waitcnt lgkmcnt(" #N ")" ::: "memory"); \
                      __builtin_amdgcn_sched_barrier(0); } while (0)

// ANTI-PHASE WAVE GROUPS. 128x256 tile, 8 waves = 2 groups of 4 (grp=wave>>2
// -> each SIMD holds one wave of EACH group). Group g owns output n-half g:
// private LDS (64KB/group: dbuf x {A-copy 16KB + B-half 16KB}), A duplicated
// across groups (costs L2 BW only). Both groups run the same 2-phase loop
// OFFSET BY ONE PHASE:
//   P1: g0 issues reads(t)+stage(t+1) | g1 WAITL->MFMA(t-1)->WAITV(0)
//   P2: g0 WAITL->MFMA(t)->WAITV(0)   | g1 issues reads(t)+stage(t+1)
// => matrix pipe and DS pipe are both fed in EVERY phase (lockstep DS/MFMA
// alternation was the 49% wall in r2/r8/r15). Hazard proof: stage(u+1) at
// the read-phase targets the buffer whose readers (own group, reads(u-1))
// WAITL-drained before a barrier all waves crossed. Depth-1 staging:
// WAITV(0) sits ~1400cyc after stage issue (> 900cyc HBM). Reads have a
// full MFMA phase (~620cyc) to complete before their WAITL.
// r2's verified 0-conflict LDS layout (row stride 128B, XOR (l15&7)<<4).
__global__ __launch_bounds__(512, 2) void gemm_pc(
    const unsigned short* __restrict__ A, const unsigned short* __restrict__ B,
    const float* __restrict__ bias, float* __restrict__ C,
    int M, int N, int K) {
    __shared__ __align__(16) char lds[131072];
    const int tid  = threadIdx.x;
    const int lane = tid & 63;
    const int wave = tid >> 6;
    const int grp  = wave >> 2;      // 0..1 (SIMD i holds waves i and i+4)
    const int w2   = wave & 3;
    const int wr   = w2 >> 1;        // 0..1 (m 64-half)
    const int wc   = w2 & 1;         // 0..1 (n 64-half within group's 128)
    const int l15  = lane & 15;
    const int l4   = lane >> 4;
    const int tg   = tid & 255;      // thread id within group

    // supertile: M-tile=128, N-tile=256; 8m x 4n = 32 blocks/XCD batch.
    const int nwg = gridDim.x;
    const int Mt  = M >> 7;
    const int Nt  = N >> 8;
    const int bid = blockIdx.x;
    int tm, tn;
    if ((Mt & 7) == 0 && (Nt & 3) == 0 && (nwg & 255) == 0) {
        const int nst = nwg >> 5;
        const int q2  = nst >> 3;
        const int xc  = bid & 7;
        const int oo  = bid >> 3;
        const int idx = oo & 31;
        const int h   = oo >> 5;
        const int st  = xc * q2 + h;
        const int Mst = Mt >> 3;
        const int stm = st % Mst;
        const int stn = st / Mst;
        tm = stm * 8 + (idx & 7);
        tn = stn * 4 + (idx >> 3);
    } else {
        int qq = nwg >> 3, rr = nwg & 7, xc = bid & 7, oo = bid >> 3;
        int wg = (xc < rr ? xc * (qq + 1) : rr * (qq + 1) + (xc - rr) * qq) + oo;
        tm = wg / Nt; tn = wg % Nt;
    }
    const long m0 = (long)tm << 7;
    const long n0 = (long)tn << 8;

    const int colSw = ((tg & 7) ^ ((tg >> 3) & 7)) << 3;
    const int rowT  = tg >> 3;       // 0..31
    const long Kl = K;
    char* baseg = lds + (grp << 16); // 64KB per group

    // stage tile t into group-private buf: A[128][64] (16KB) + B-half (16KB)
    auto STAGE = [&](int buf, int t) {
        char* dA = baseg + (buf << 15) + tg * 16;
        char* dB = dA + 16384;
        long col = (long)t * 64 + colSw;
#pragma unroll
        for (int j = 0; j < 4; ++j)
            GLL(A + (m0 + rowT + j * 32) * Kl + col, dA + j * 4096);
#pragma unroll
        for (int j = 0; j < 4; ++j)
            GLL(B + (n0 + grp * 128 + rowT + j * 32) * Kl + col, dB + j * 4096);
    };
    auto LDA = [&](int buf, int m, int kk) -> bf16x8 {
        int off = (((wr * 64 + m * 16 + l15) * 64 + kk * 32 + l4 * 8) * 2) ^ ((l15 & 7) << 4);
        return *(const bf16x8*)(baseg + (buf << 15) + off);
    };
    auto LDB = [&](int buf, int n, int kk) -> bf16x8 {
        int off = (((wc * 64 + n * 16 + l15) * 64 + kk * 32 + l4 * 8) * 2) ^ ((l15 & 7) << 4);
        return *(const bf16x8*)(baseg + (buf << 15) + 16384 + off);
    };

    f32x4 acc[4][4] = {};            // 64 regs
    bf16x8 af[4][2], bq[4][2];       // 64 regs

    auto RD_ALL = [&](int buf) {
#pragma unroll
        for (int m = 0; m < 4; ++m) { af[m][0] = LDA(buf, m, 0); af[m][1] = LDA(buf, m, 1); }
#pragma unroll
        for (int n = 0; n < 4; ++n) { bq[n][0] = LDB(buf, n, 0); bq[n][1] = LDB(buf, n, 1); }
    };
    auto MFMA_ALL = [&]() {
        __builtin_amdgcn_s_setprio(1);
#pragma unroll
        for (int kk = 0; kk < 2; ++kk)
#pragma unroll
            for (int m = 0; m < 4; ++m)
#pragma unroll
                for (int n = 0; n < 4; ++n)
                    acc[m][n] = __builtin_amdgcn_mfma_f32_16x16x32_bf16(
                        af[m][kk], bq[n][kk], acc[m][n], 0, 0, 0);
        __builtin_amdgcn_s_setprio(0);
    };

    const int NT = K >> 6;

    // prologue (both groups): stage tile 0, full drain, publish
    STAGE(0, 0);
    WAITV(0);
    BARRIER();

    for (int t = 0; t < NT; ++t) {
        const int c = t & 1;
        // ---- P1: g0 read-phase | g1 mfma-phase ----
        if (grp == 0) {
            RD_ALL(c);
            if (t + 1 < NT) STAGE(c ^ 1, t + 1);
        } else {
            if (t > 0) { WAITL(0); MFMA_ALL(); }
            WAITV(0);                // stage(t) drained (issued P2(t-1), ~1.4k cyc ago)
        }
        BARRIER();
        // ---- P2: g0 mfma-phase | g1 read-phase ----
        if (grp == 0) {
            WAITL(0); MFMA_ALL();
            WAITV(0);                // stage(t+1) drained (issued P1(t))
        } else {
            RD_ALL(c);
            if (t + 1 < NT) STAGE(c ^ 1, t + 1);
        }
        BARRIER();
    }
    if (grp == 1) { WAITL(0); MFMA_ALL(); }   // g1 finishes tile NT-1

    // epilogue: group g writes cols n0+g*128..+128; D mapping col=l15,row=l4*4+j
#pragma unroll
    for (int n = 0; n < 4; ++n) {
        const long col = n0 + grp * 128 + wc * 64 + n * 16 + l15;
        const float bv = bias[col];
#pragma unroll
        for (int m = 0; m < 4; ++m) {
            float* Cp = C + (m0 + wr * 64 + m * 16 + l4 * 4) * (long)N + col;
#pragma unroll
            for (int j = 0; j < 4; ++j)
                Cp[(long)j * N] = acc[m][n][j] + bv;
        }
    }
}

// fallback: m97-structure 128x128 (verified round 1)
__global__ __launch_bounds__(256) void gemm_bt_bias(const unsigned short* __restrict__ A,
                                                    const unsigned short* __restrict__ B,
                                                    const float* __restrict__ bias,
                                                    float* __restrict__ C,
                                                    int M, int N, int K) {
    __shared__ unsigned short lds_a[128 * 32];
    __shared__ unsigned short lds_b[128 * 32];
    const int tid  = threadIdx.x;
    const int lane = tid & 63;
    const int wave = tid >> 6;
    const int wrr = wave >> 1, wcc = wave & 1;
    const int l15 = lane & 15, l4 = lane >> 4;
    const int nTilesN = N / 128;
    const long m0 = (long)(blockIdx.x / nTilesN) * 128;
    const long n0 = (long)(blockIdx.x % nTilesN) * 128;
    f32x4 acc[4][4] = {};
    const unsigned short* aSrc = A + (m0 + (tid >> 2)) * (long)K + ((tid & 3) * 8);
    const unsigned short* bSrc = B + (n0 + (tid >> 2)) * (long)K + ((tid & 3) * 8);
    char* aDst = (char*)lds_a + tid * 16;
    char* bDst = (char*)lds_b + tid * 16;
    for (int k0 = 0; k0 < K; k0 += 32) {
#pragma unroll
        for (int i = 0; i < 2; i++) {
            GLL(aSrc + (long)i * 64 * K + k0, aDst + i * 4096);
            GLL(bSrc + (long)i * 64 * K + k0, bDst + i * 4096);
        }
        __syncthreads();
        bf16x8 afr[4], bfr[4];
#pragma unroll
        for (int r = 0; r < 4; r++)
            afr[r] = *(const bf16x8*)&lds_a[(wrr * 64 + r * 16 + l15) * 32 + l4 * 8];
#pragma unroll
        for (int c = 0; c < 4; c++)
            bfr[c] = *(const bf16x8*)&lds_b[(wcc * 64 + c * 16 + l15) * 32 + l4 * 8];
#pragma unroll
        for (int r = 0; r < 4; r++)
#pragma unroll
            for (int c = 0; c < 4; c++)
                acc[r][c] = __builtin_amdgcn_mfma_f32_16x16x32_bf16(afr[r], bfr[c], acc[r][c], 0, 0, 0);
        __syncthreads();
    }
#pragma unroll
    for (int c = 0; c < 4; c++) {
        const long n = n0 + wcc * 64 + c * 16 + l15;
        const float bv = bias[n];
#pragma unroll
        for (int r = 0; r < 4; r++) {
            const long m = m0 + wrr * 64 + r * 16 + l4 * 4;
            float* Cp = C + m * (long)N + n;
#pragma unroll
            for (int j = 0; j < 4; j++)
                Cp[(long)j * N] = acc[r][c][j] + bv;
        }
    }
}

extern "C" void kernel_launch(void* const* d_in, const int* in_sizes, int n_in,
                              void* d_out, int out_size, void* d_ws, size_t ws_size,
                              hipStream_t stream) {
    const float* x    = (const float*)d_in[0];
    const float* w    = (const float*)d_in[1];
    const float* bias = (const float*)d_in[2];
    float* out = (float*)d_out;

    const long Nn = in_sizes[2];             // OUT = 4096
    const long Kk = (long)in_sizes[1] / Nn;  // IN  = 16384
    const long Mm = (long)in_sizes[0] / Kk;  // B*S = 8192

    unsigned short* aB = (unsigned short*)d_ws;
    unsigned short* bB = aB + Mm * Kk;
    cvt_f32_bf16<<<2048, 256, 0, stream>>>(x, aB, Mm * Kk);
    cvt_f32_bf16<<<2048, 256, 0, stream>>>(w, bB, Nn * Kk);

    if ((Mm & 127) == 0 && (Nn & 255) == 0 && (Kk & 63) == 0 && Kk >= 192) {
        const int grid = (int)((Mm >> 7) * (Nn >> 8));
        gemm_pc<<<grid, 512, 0, stream>>>(aB, bB, bias, out, (int)Mm, (int)Nn, (int)Kk);
    } else {
        const int grid = (int)((Mm / 128) * (Nn / 128));
        gemm_bt_bias<<<grid, 256, 0, stream>>>(aB, bB, bias, out, (int)Mm, (int)Nn, (int)Kk);
    }
}

// Round 18
// 1105.474 us; speedup vs baseline: 1.4158x; 1.2372x over previous
//
#include <hip/hip_runtime.h>
#include <hip/hip_bf16.h>
#include <stdint.h>

typedef float  f32x4  __attribute__((ext_vector_type(4)));
typedef __bf16 bf16x8 __attribute__((ext_vector_type(8)));
typedef unsigned short u16x8 __attribute__((ext_vector_type(8)));

__device__ __forceinline__ unsigned short f2bf_rne(float f) {
    uint32_t x = __float_as_uint(f);
    uint32_t r = x + 0x7FFFu + ((x >> 16) & 1u);
    return (unsigned short)(r >> 16);
}

__global__ __launch_bounds__(256) void cvt_f32_bf16(const float* __restrict__ src,
                                                    unsigned short* __restrict__ dst,
                                                    long n) {
    long i0 = ((long)blockIdx.x * blockDim.x + threadIdx.x) * 8;
    long stride = (long)gridDim.x * blockDim.x * 8;
    for (long j = i0; j + 8 <= n; j += stride) {
        float4 v0 = *(const float4*)(src + j);
        float4 v1 = *(const float4*)(src + j + 4);
        u16x8 o;
        o[0] = f2bf_rne(v0.x); o[1] = f2bf_rne(v0.y);
        o[2] = f2bf_rne(v0.z); o[3] = f2bf_rne(v0.w);
        o[4] = f2bf_rne(v1.x); o[5] = f2bf_rne(v1.y);
        o[6] = f2bf_rne(v1.z); o[7] = f2bf_rne(v1.w);
        *(u16x8*)(dst + j) = o;
    }
}

#define GLL(SRC, DST) __builtin_amdgcn_global_load_lds(                      \
    (const __attribute__((address_space(1))) void*)(SRC),                    \
    (__attribute__((address_space(3))) void*)(DST), 16, 0, 0)
#define BARRIER() asm volatile("s_barrier" ::: "memory")
#define WAITV(N) asm volatile("s_waitcnt vmcnt(" #N ")" ::: "memory")
#define WAITL(N) do { asm volatile("s_waitcnt lgkmcnt(" #N ")" ::: "memory"); \
                      __builtin_amdgcn_sched_barrier(0); } while (0)

// BEST VERIFIED (round 15, 1098us total / 1020us best GEMM dispatch):
// 256x256, BK=64, 8 waves, 128KB dbuf LDS, 0-conflict swizzled layout,
// two-level XCD super-tile mapping, 2 merged phases/tile (4 barriers):
//  PhaseA: read af(u0,8)+bq(Bu0,4)+bq2(Bu1,4); stage A-u1(nxt,t+1)[deferred];
//          BAR; WAITL(0); Q00+Q01 (32 MFMA); BAR
//  PhaseB: read af2(u1,8); stage A-u0,B-u0,B-u1 (cur,t+2); WAITV(6); BAR;
//          WAITL(0); Q10+Q11 (32 MFMA); BAR
// Ledger: steady outstanding @gate = 14 = [t+1:6][t+1 A-u1:2][t+2:6];
// WAITV(6) drains oldest 8 = exactly tile t+1. WAITV(0) for t>=NT-3.
// Frag regs 96 (af/af2/bq/bq2 fixed roles), acc 128 AGPR — no spill (120 VGPR).
__global__ __launch_bounds__(512, 2) void gemm256_m2(
    const unsigned short* __restrict__ A, const unsigned short* __restrict__ B,
    const float* __restrict__ bias, float* __restrict__ C,
    int M, int N, int K) {
    __shared__ __align__(16) char lds[131072];
    const int tid  = threadIdx.x;
    const int lane = tid & 63;
    const int wave = tid >> 6;
    const int wr  = wave >> 2;   // 0..1
    const int wc  = wave & 3;    // 0..3
    const int l15 = lane & 15;
    const int l4  = lane >> 4;

    // two-level XCD super-tile mapping (round-8 verified: FETCH -37%)
    const int nwg = gridDim.x;
    const int Nt  = N >> 8;
    const int Mt  = M >> 8;
    const int bid = blockIdx.x;
    int tm, tn;
    if ((Mt & 7) == 0 && (Nt & 3) == 0 && (nwg & 255) == 0) {
        const int nst = nwg >> 5;
        const int q2  = nst >> 3;
        const int xc  = bid & 7;
        const int oo  = bid >> 3;
        const int idx = oo & 31;
        const int h   = oo >> 5;
        const int st  = xc * q2 + h;
        const int Mst = Mt >> 3;
        const int stm = st % Mst;
        const int stn = st / Mst;
        tm = stm * 8 + (idx & 7);
        tn = stn * 4 + (idx >> 3);
    } else {
        int qq = nwg >> 3, rr = nwg & 7, xc = bid & 7, oo = bid >> 3;
        int wg = (xc < rr ? xc * (qq + 1) : rr * (qq + 1) + (xc - rr) * qq) + oo;
        tm = wg / Nt; tn = wg % Nt;
    }
    const long m0 = (long)tm << 8;
    const long n0 = (long)tn << 8;

    const int colSw = ((tid & 7) ^ ((tid >> 3) & 7)) << 3;
    const int aRow  = tid >> 3;
    const int bWcLo = tid >> 8;
    const int bR    = (tid >> 3) & 31;
    const long Kl = K;

    auto STAGE_A = [&](int buf, int u, int t) {
        char* dst = lds + (buf << 16) + (u << 14) + tid * 16;
        long col = (long)t * 64 + colSw;
#pragma unroll
        for (int i = 0; i < 2; ++i) {
            const unsigned short* src = A + (m0 + i * 128 + u * 64 + aRow) * Kl + col;
            GLL(src, dst + i * 8192);
        }
    };
    auto STAGE_B = [&](int buf, int u, int t) {
        char* dst = lds + (buf << 16) + 32768 + (u << 14) + tid * 16;
        long col = (long)t * 64 + colSw;
#pragma unroll
        for (int i = 0; i < 2; ++i) {
            const unsigned short* src = B + (n0 + (i * 2 + bWcLo) * 64 + u * 32 + bR) * Kl + col;
            GLL(src, dst + i * 8192);
        }
    };
    auto LDA = [&](int buf, int mh, int m, int kk) -> bf16x8 {
        int off = (((m * 16 + l15) * 64 + kk * 32 + l4 * 8) * 2) ^ ((l15 & 7) << 4);
        return *(const bf16x8*)(lds + (buf << 16) + (mh << 14) + (wr << 13) + off);
    };
    auto LDB = [&](int buf, int nh, int n, int kk) -> bf16x8 {
        int off = (((n * 16 + l15) * 64 + kk * 32 + l4 * 8) * 2) ^ ((l15 & 7) << 4);
        return *(const bf16x8*)(lds + (buf << 16) + 32768 + (nh << 14) + (wc << 12) + off);
    };

    f32x4 acc[8][4] = {};                 // 128 AGPR
    bf16x8 af[4][2], af2[4][2];           // fixed roles: mh0 / mh1
    bf16x8 bq[2][2], bq2[2][2];           // fixed roles: nh0 / nh1

    auto RD_A = [&](bf16x8 (&d)[4][2], int buf, int mh) {
#pragma unroll
        for (int m = 0; m < 4; ++m) { d[m][0] = LDA(buf, mh, m, 0); d[m][1] = LDA(buf, mh, m, 1); }
    };
    auto RD_B = [&](bf16x8 (&d)[2][2], int buf, int nh) {
#pragma unroll
        for (int n = 0; n < 2; ++n) { d[n][0] = LDB(buf, nh, n, 0); d[n][1] = LDB(buf, nh, n, 1); }
    };
    auto MFMA_Q = [&](bf16x8 (&a_)[4][2], bf16x8 (&b_)[2][2], int mo, int no) {
        __builtin_amdgcn_s_setprio(1);
#pragma unroll
        for (int kk = 0; kk < 2; ++kk)
#pragma unroll
            for (int m = 0; m < 4; ++m)
#pragma unroll
                for (int n = 0; n < 2; ++n)
                    acc[mo + m][no + n] = __builtin_amdgcn_mfma_f32_16x16x32_bf16(
                        a_[m][kk], b_[n][kk], acc[mo + m][no + n], 0, 0, 0);
        __builtin_amdgcn_s_setprio(0);
    };

    const int NT = K >> 6;

    // prologue: t0 all 4 units (8 GLL); t1 {A-u0, B-u0, B-u1} (6 GLL);
    // WAITV(6) drains t0's 8, leaves t1's 6 in flight; barrier publishes t0.
    STAGE_A(0, 0, 0); STAGE_A(0, 1, 0); STAGE_B(0, 0, 0); STAGE_B(0, 1, 0);
    STAGE_A(1, 0, 1); STAGE_B(1, 0, 1); STAGE_B(1, 1, 1);
    WAITV(6);
    BARRIER();

    for (int t = 0; t < NT; ++t) {
        const int cur = t & 1, nxt = cur ^ 1;
        // ---- PhaseA: reads af,bq,bq2 ; deferred stage A-u1(nxt,t+1) ----
        RD_A(af, cur, 0);                 // 8 ds (A unit0)
        RD_B(bq, cur, 0);                 // 4 ds (B unit0)
        RD_B(bq2, cur, 1);                // 4 ds (B unit1)
        if (t + 1 < NT) STAGE_A(nxt, 1, t + 1);   // 2 GLL
        BARRIER(); WAITL(0);
        MFMA_Q(af, bq, 0, 0);             // Q00
        MFMA_Q(af, bq2, 0, 2);            // Q01
        BARRIER();
        // ---- PhaseB: read af2 ; stage 3 units (cur,t+2) ; gate ; MFMA ----
        RD_A(af2, cur, 1);                // 8 ds (A unit1)
        if (t + 2 < NT) {
            STAGE_A(cur, 0, t + 2);
            STAGE_B(cur, 0, t + 2);
            STAGE_B(cur, 1, t + 2);       // 6 GLL
        }
        if (t >= NT - 3) { WAITV(0); } else { WAITV(6); }
        BARRIER(); WAITL(0);
        MFMA_Q(af2, bq, 4, 0);            // Q10
        MFMA_Q(af2, bq2, 4, 2);           // Q11
        BARRIER();
    }

    // epilogue: D mapping col = l15, row = l4*4 + j within each 16x16 fragment
#pragma unroll
    for (int nf = 0; nf < 4; ++nf) {
        const long col = n0 + wc * 64 + nf * 16 + l15;
        const float bv = bias[col];
#pragma unroll
        for (int mf = 0; mf < 8; ++mf) {
            float* Cp = C + (m0 + wr * 128 + mf * 16 + l4 * 4) * (long)N + col;
#pragma unroll
            for (int j = 0; j < 4; ++j)
                Cp[(long)j * N] = acc[mf][nf][j] + bv;
        }
    }
}

// fallback: m97-structure 128x128 (verified round 1)
__global__ __launch_bounds__(256) void gemm_bt_bias(const unsigned short* __restrict__ A,
                                                    const unsigned short* __restrict__ B,
                                                    const float* __restrict__ bias,
                                                    float* __restrict__ C,
                                                    int M, int N, int K) {
    __shared__ unsigned short lds_a[128 * 32];
    __shared__ unsigned short lds_b[128 * 32];
    const int tid  = threadIdx.x;
    const int lane = tid & 63;
    const int wave = tid >> 6;
    const int wrr = wave >> 1, wcc = wave & 1;
    const int l15 = lane & 15, l4 = lane >> 4;
    const int nTilesN = N / 128;
    const long m0 = (long)(blockIdx.x / nTilesN) * 128;
    const long n0 = (long)(blockIdx.x % nTilesN) * 128;
    f32x4 acc[4][4] = {};
    const unsigned short* aSrc = A + (m0 + (tid >> 2)) * (long)K + ((tid & 3) * 8);
    const unsigned short* bSrc = B + (n0 + (tid >> 2)) * (long)K + ((tid & 3) * 8);
    char* aDst = (char*)lds_a + tid * 16;
    char* bDst = (char*)lds_b + tid * 16;
    for (int k0 = 0; k0 < K; k0 += 32) {
#pragma unroll
        for (int i = 0; i < 2; i++) {
            GLL(aSrc + (long)i * 64 * K + k0, aDst + i * 4096);
            GLL(bSrc + (long)i * 64 * K + k0, bDst + i * 4096);
        }
        __syncthreads();
        bf16x8 afr[4], bfr[4];
#pragma unroll
        for (int r = 0; r < 4; r++)
            afr[r] = *(const bf16x8*)&lds_a[(wrr * 64 + r * 16 + l15) * 32 + l4 * 8];
#pragma unroll
        for (int c = 0; c < 4; c++)
            bfr[c] = *(const bf16x8*)&lds_b[(wcc * 64 + c * 16 + l15) * 32 + l4 * 8];
#pragma unroll
        for (int r = 0; r < 4; r++)
#pragma unroll
            for (int c = 0; c < 4; c++)
                acc[r][c] = __builtin_amdgcn_mfma_f32_16x16x32_bf16(afr[r], bfr[c], acc[r][c], 0, 0, 0);
        __syncthreads();
    }
#pragma unroll
    for (int c = 0; c < 4; c++) {
        const long n = n0 + wcc * 64 + c * 16 + l15;
        const float bv = bias[n];
#pragma unroll
        for (int r = 0; r < 4; r++) {
            const long m = m0 + wrr * 64 + r * 16 + l4 * 4;
            float* Cp = C + m * (long)N + n;
#pragma unroll
            for (int j = 0; j < 4; j++)
                Cp[(long)j * N] = acc[r][c][j] + bv;
        }
    }
}

extern "C" void kernel_launch(void* const* d_in, const int* in_sizes, int n_in,
                              void* d_out, int out_size, void* d_ws, size_t ws_size,
                              hipStream_t stream) {
    const float* x    = (const float*)d_in[0];
    const float* w    = (const float*)d_in[1];
    const float* bias = (const float*)d_in[2];
    float* out = (float*)d_out;

    const long Nn = in_sizes[2];             // OUT = 4096
    const long Kk = (long)in_sizes[1] / Nn;  // IN  = 16384
    const long Mm = (long)in_sizes[0] / Kk;  // B*S = 8192

    unsigned short* aB = (unsigned short*)d_ws;
    unsigned short* bB = aB + Mm * Kk;
    cvt_f32_bf16<<<2048, 256, 0, stream>>>(x, aB, Mm * Kk);
    cvt_f32_bf16<<<2048, 256, 0, stream>>>(w, bB, Nn * Kk);

    if ((Mm & 255) == 0 && (Nn & 255) == 0 && (Kk & 127) == 0 && Kk >= 256) {
        const int grid = (int)((Mm >> 8) * (Nn >> 8));
        gemm256_m2<<<grid, 512, 0, stream>>>(aB, bB, bias, out, (int)Mm, (int)Nn, (int)Kk);
    } else {
        const int grid = (int)((Mm / 128) * (Nn / 128));
        gemm_bt_bias<<<grid, 256, 0, stream>>>(aB, bB, bias, out, (int)Mm, (int)Nn, (int)Kk);
    }
}

// Round 19
// 1103.302 us; speedup vs baseline: 1.4186x; 1.0020x over previous
//
#include <hip/hip_runtime.h>
#include <hip/hip_bf16.h>
#include <stdint.h>

typedef float  f32x4  __attribute__((ext_vector_type(4)));
typedef __bf16 bf16x8 __attribute__((ext_vector_type(8)));
typedef unsigned short u16x8 __attribute__((ext_vector_type(8)));

__device__ __forceinline__ unsigned short f2bf_rne(float f) {
    uint32_t x = __float_as_uint(f);
    uint32_t r = x + 0x7FFFu + ((x >> 16) & 1u);
    return (unsigned short)(r >> 16);
}

__global__ __launch_bounds__(256) void cvt_f32_bf16(const float* __restrict__ src,
                                                    unsigned short* __restrict__ dst,
                                                    long n) {
    long i0 = ((long)blockIdx.x * blockDim.x + threadIdx.x) * 8;
    long stride = (long)gridDim.x * blockDim.x * 8;
    for (long j = i0; j + 8 <= n; j += stride) {
        float4 v0 = *(const float4*)(src + j);
        float4 v1 = *(const float4*)(src + j + 4);
        u16x8 o;
        o[0] = f2bf_rne(v0.x); o[1] = f2bf_rne(v0.y);
        o[2] = f2bf_rne(v0.z); o[3] = f2bf_rne(v0.w);
        o[4] = f2bf_rne(v1.x); o[5] = f2bf_rne(v1.y);
        o[6] = f2bf_rne(v1.z); o[7] = f2bf_rne(v1.w);
        *(u16x8*)(dst + j) = o;
    }
}

#define GLL(SRC, DST) __builtin_amdgcn_global_load_lds(                      \
    (const __attribute__((address_space(1))) void*)(SRC),                    \
    (__attribute__((address_space(3))) void*)(DST), 16, 0, 0)
#define BARRIER() asm volatile("s_barrier" ::: "memory")
#define WAITV(N) asm volatile("s_waitcnt vmcnt(" #N ")" ::: "memory")
#define WAITL(N) do { asm volatile("s_waitcnt lgkmcnt(" #N ")" ::: "memory"); \
                      __builtin_amdgcn_sched_barrier(0); } while (0)

// r15 skeleton (verified 1020us / 49% / 0 conflicts / no spill) with ONE
// change: INTRA-PHASE fragment-level interleave. Half of each phase's
// ds_reads are issued AFTER the pre-MFMA WAITL(0), inside the MFMA cluster,
// with counted lgkm drains between m-rows -- so those reads complete under
// MFMA issue instead of in an exposed DS burst (m196/m201's fine-interleave
// lever, never actually tested in rounds 2-18: all prior variants clustered
// reads pre-barrier).
//  PhaseA: pre-bar read af[0..1](4)+bq(4); stage A-u1(t+1); BAR; WAITL(0);
//          issue af[2..3](4)+bq2(4); Q00 m0,m1 (8 MFMA); WAITL(6);
//          m2 (4); WAITL(4); m3 (4); WAITL(0); Q01 (16); BAR
//  PhaseB: pre-bar read af2[0..1](4); stage 3 units(t+2); vm gate; BAR;
//          WAITL(0); issue af2[2..3](4); Q10 m0,m1 (8); WAITL(2); m2 (4);
//          WAITL(0); m3 (4); Q11 (16); BAR
// Hazards: identical to r15 (late reads target buf cur; overwrite >=2
// barriers away; WAITL ledger counts ds_reads only -- GLL is vmcnt).
// vmcnt ledger unchanged: WAITV(6)@PhaseB drains exactly tile t+1.
__global__ __launch_bounds__(512, 2) void gemm256_il(
    const unsigned short* __restrict__ A, const unsigned short* __restrict__ B,
    const float* __restrict__ bias, float* __restrict__ C,
    int M, int N, int K) {
    __shared__ __align__(16) char lds[131072];
    const int tid  = threadIdx.x;
    const int lane = tid & 63;
    const int wave = tid >> 6;
    const int wr  = wave >> 2;   // 0..1
    const int wc  = wave & 3;    // 0..3
    const int l15 = lane & 15;
    const int l4  = lane >> 4;

    // two-level XCD super-tile mapping (round-8 verified: FETCH -37%)
    const int nwg = gridDim.x;
    const int Nt  = N >> 8;
    const int Mt  = M >> 8;
    const int bid = blockIdx.x;
    int tm, tn;
    if ((Mt & 7) == 0 && (Nt & 3) == 0 && (nwg & 255) == 0) {
        const int nst = nwg >> 5;
        const int q2  = nst >> 3;
        const int xc  = bid & 7;
        const int oo  = bid >> 3;
        const int idx = oo & 31;
        const int h   = oo >> 5;
        const int st  = xc * q2 + h;
        const int Mst = Mt >> 3;
        const int stm = st % Mst;
        const int stn = st / Mst;
        tm = stm * 8 + (idx & 7);
        tn = stn * 4 + (idx >> 3);
    } else {
        int qq = nwg >> 3, rr = nwg & 7, xc = bid & 7, oo = bid >> 3;
        int wg = (xc < rr ? xc * (qq + 1) : rr * (qq + 1) + (xc - rr) * qq) + oo;
        tm = wg / Nt; tn = wg % Nt;
    }
    const long m0 = (long)tm << 8;
    const long n0 = (long)tn << 8;

    const int colSw = ((tid & 7) ^ ((tid >> 3) & 7)) << 3;
    const int aRow  = tid >> 3;
    const int bWcLo = tid >> 8;
    const int bR    = (tid >> 3) & 31;
    const long Kl = K;

    auto STAGE_A = [&](int buf, int u, int t) {
        char* dst = lds + (buf << 16) + (u << 14) + tid * 16;
        long col = (long)t * 64 + colSw;
#pragma unroll
        for (int i = 0; i < 2; ++i) {
            const unsigned short* src = A + (m0 + i * 128 + u * 64 + aRow) * Kl + col;
            GLL(src, dst + i * 8192);
        }
    };
    auto STAGE_B = [&](int buf, int u, int t) {
        char* dst = lds + (buf << 16) + 32768 + (u << 14) + tid * 16;
        long col = (long)t * 64 + colSw;
#pragma unroll
        for (int i = 0; i < 2; ++i) {
            const unsigned short* src = B + (n0 + (i * 2 + bWcLo) * 64 + u * 32 + bR) * Kl + col;
            GLL(src, dst + i * 8192);
        }
    };
    auto LDA = [&](int buf, int mh, int m, int kk) -> bf16x8 {
        int off = (((m * 16 + l15) * 64 + kk * 32 + l4 * 8) * 2) ^ ((l15 & 7) << 4);
        return *(const bf16x8*)(lds + (buf << 16) + (mh << 14) + (wr << 13) + off);
    };
    auto LDB = [&](int buf, int nh, int n, int kk) -> bf16x8 {
        int off = (((n * 16 + l15) * 64 + kk * 32 + l4 * 8) * 2) ^ ((l15 & 7) << 4);
        return *(const bf16x8*)(lds + (buf << 16) + 32768 + (nh << 14) + (wc << 12) + off);
    };

    f32x4 acc[8][4] = {};                 // 128 AGPR
    bf16x8 af[4][2], af2[4][2];           // fixed roles: mh0 / mh1
    bf16x8 bq[2][2], bq2[2][2];           // fixed roles: nh0 / nh1

    auto RD_A2 = [&](bf16x8 (&d)[4][2], int buf, int mh, int half) {
#pragma unroll
        for (int m = half * 2; m < half * 2 + 2; ++m) {
            d[m][0] = LDA(buf, mh, m, 0); d[m][1] = LDA(buf, mh, m, 1);
        }
    };
    auto RD_B = [&](bf16x8 (&d)[2][2], int buf, int nh) {
#pragma unroll
        for (int n = 0; n < 2; ++n) { d[n][0] = LDB(buf, nh, n, 0); d[n][1] = LDB(buf, nh, n, 1); }
    };
    // one m-row of a quadrant: 4 MFMAs (kk x n)
    auto MFMA_M = [&](bf16x8 (&a_)[4][2], int m, bf16x8 (&b_)[2][2], int mo, int no) {
#pragma unroll
        for (int kk = 0; kk < 2; ++kk)
#pragma unroll
            for (int n = 0; n < 2; ++n)
                acc[mo + m][no + n] = __builtin_amdgcn_mfma_f32_16x16x32_bf16(
                    a_[m][kk], b_[n][kk], acc[mo + m][no + n], 0, 0, 0);
    };

    const int NT = K >> 6;

    // prologue: t0 all 4 units (8 GLL); t1 {A-u0, B-u0, B-u1} (6 GLL);
    // WAITV(6) drains t0's 8, leaves t1's 6 in flight; barrier publishes t0.
    STAGE_A(0, 0, 0); STAGE_A(0, 1, 0); STAGE_B(0, 0, 0); STAGE_B(0, 1, 0);
    STAGE_A(1, 0, 1); STAGE_B(1, 0, 1); STAGE_B(1, 1, 1);
    WAITV(6);
    BARRIER();

    for (int t = 0; t < NT; ++t) {
        const int cur = t & 1, nxt = cur ^ 1;
        // ---- PhaseA ----
        RD_A2(af, cur, 0, 0);             // af[0..1]: 4 ds
        RD_B(bq, cur, 0);                 // 4 ds
        if (t + 1 < NT) STAGE_A(nxt, 1, t + 1);   // 2 GLL (deferred A-u1)
        BARRIER(); WAITL(0);
        RD_A2(af, cur, 0, 1);             // af[2..3]: 4 ds (late)
        RD_B(bq2, cur, 1);                // 4 ds (late)
        __builtin_amdgcn_s_setprio(1);
        MFMA_M(af, 0, bq, 0, 0);          // Q00 m0
        MFMA_M(af, 1, bq, 0, 0);          // Q00 m1
        WAITL(6);                         // af[2] ready
        MFMA_M(af, 2, bq, 0, 0);
        WAITL(4);                         // af[3] ready
        MFMA_M(af, 3, bq, 0, 0);
        WAITL(0);                         // bq2 ready
#pragma unroll
        for (int m = 0; m < 4; ++m) MFMA_M(af, m, bq2, 0, 2);   // Q01
        __builtin_amdgcn_s_setprio(0);
        BARRIER();
        // ---- PhaseB ----
        RD_A2(af2, cur, 1, 0);            // af2[0..1]: 4 ds
        if (t + 2 < NT) {
            STAGE_A(cur, 0, t + 2);
            STAGE_B(cur, 0, t + 2);
            STAGE_B(cur, 1, t + 2);       // 6 GLL
        }
        if (t >= NT - 3) { WAITV(0); } else { WAITV(6); }
        BARRIER(); WAITL(0);
        RD_A2(af2, cur, 1, 1);            // af2[2..3]: 4 ds (late)
        __builtin_amdgcn_s_setprio(1);
        MFMA_M(af2, 0, bq, 4, 0);         // Q10 m0
        MFMA_M(af2, 1, bq, 4, 0);         // Q10 m1
        WAITL(2);                         // af2[2] ready
        MFMA_M(af2, 2, bq, 4, 0);
        WAITL(0);                         // af2[3] ready
        MFMA_M(af2, 3, bq, 4, 0);
#pragma unroll
        for (int m = 0; m < 4; ++m) MFMA_M(af2, m, bq2, 4, 2);  // Q11
        __builtin_amdgcn_s_setprio(0);
        BARRIER();
    }

    // epilogue: D mapping col = l15, row = l4*4 + j within each 16x16 fragment
#pragma unroll
    for (int nf = 0; nf < 4; ++nf) {
        const long col = n0 + wc * 64 + nf * 16 + l15;
        const float bv = bias[col];
#pragma unroll
        for (int mf = 0; mf < 8; ++mf) {
            float* Cp = C + (m0 + wr * 128 + mf * 16 + l4 * 4) * (long)N + col;
#pragma unroll
            for (int j = 0; j < 4; ++j)
                Cp[(long)j * N] = acc[mf][nf][j] + bv;
        }
    }
}

// fallback: m97-structure 128x128 (verified round 1)
__global__ __launch_bounds__(256) void gemm_bt_bias(const unsigned short* __restrict__ A,
                                                    const unsigned short* __restrict__ B,
                                                    const float* __restrict__ bias,
                                                    float* __restrict__ C,
                                                    int M, int N, int K) {
    __shared__ unsigned short lds_a[128 * 32];
    __shared__ unsigned short lds_b[128 * 32];
    const int tid  = threadIdx.x;
    const int lane = tid & 63;
    const int wave = tid >> 6;
    const int wrr = wave >> 1, wcc = wave & 1;
    const int l15 = lane & 15, l4 = lane >> 4;
    const int nTilesN = N / 128;
    const long m0 = (long)(blockIdx.x / nTilesN) * 128;
    const long n0 = (long)(blockIdx.x % nTilesN) * 128;
    f32x4 acc[4][4] = {};
    const unsigned short* aSrc = A + (m0 + (tid >> 2)) * (long)K + ((tid & 3) * 8);
    const unsigned short* bSrc = B + (n0 + (tid >> 2)) * (long)K + ((tid & 3) * 8);
    char* aDst = (char*)lds_a + tid * 16;
    char* bDst = (char*)lds_b + tid * 16;
    for (int k0 = 0; k0 < K; k0 += 32) {
#pragma unroll
        for (int i = 0; i < 2; i++) {
            GLL(aSrc + (long)i * 64 * K + k0, aDst + i * 4096);
            GLL(bSrc + (long)i * 64 * K + k0, bDst + i * 4096);
        }
        __syncthreads();
        bf16x8 afr[4], bfr[4];
#pragma unroll
        for (int r = 0; r < 4; r++)
            afr[r] = *(const bf16x8*)&lds_a[(wrr * 64 + r * 16 + l15) * 32 + l4 * 8];
#pragma unroll
        for (int c = 0; c < 4; c++)
            bfr[c] = *(const bf16x8*)&lds_b[(wcc * 64 + c * 16 + l15) * 32 + l4 * 8];
#pragma unroll
        for (int r = 0; r < 4; r++)
#pragma unroll
            for (int c = 0; c < 4; c++)
                acc[r][c] = __builtin_amdgcn_mfma_f32_16x16x32_bf16(afr[r], bfr[c], acc[r][c], 0, 0, 0);
        __syncthreads();
    }
#pragma unroll
    for (int c = 0; c < 4; c++) {
        const long n = n0 + wcc * 64 + c * 16 + l15;
        const float bv = bias[n];
#pragma unroll
        for (int r = 0; r < 4; r++) {
            const long m = m0 + wrr * 64 + r * 16 + l4 * 4;
            float* Cp = C + m * (long)N + n;
#pragma unroll
            for (int j = 0; j < 4; j++)
                Cp[(long)j * N] = acc[r][c][j] + bv;
        }
    }
}

extern "C" void kernel_launch(void* const* d_in, const int* in_sizes, int n_in,
                              void* d_out, int out_size, void* d_ws, size_t ws_size,
                              hipStream_t stream) {
    const float* x    = (const float*)d_in[0];
    const float* w    = (const float*)d_in[1];
    const float* bias = (const float*)d_in[2];
    float* out = (float*)d_out;

    const long Nn = in_sizes[2];             // OUT = 4096
    const long Kk = (long)in_sizes[1] / Nn;  // IN  = 16384
    const long Mm = (long)in_sizes[0] / Kk;  // B*S = 8192

    unsigned short* aB = (unsigned short*)d_ws;
    unsigned short* bB = aB + Mm * Kk;
    cvt_f32_bf16<<<2048, 256, 0, stream>>>(x, aB, Mm * Kk);
    cvt_f32_bf16<<<2048, 256, 0, stream>>>(w, bB, Nn * Kk);

    if ((Mm & 255) == 0 && (Nn & 255) == 0 && (Kk & 127) == 0 && Kk >= 256) {
        const int grid = (int)((Mm >> 8) * (Nn >> 8));
        gemm256_il<<<grid, 512, 0, stream>>>(aB, bB, bias, out, (int)Mm, (int)Nn, (int)Kk);
    } else {
        const int grid = (int)((Mm / 128) * (Nn / 128));
        gemm_bt_bias<<<grid, 256, 0, stream>>>(aB, bB, bias, out, (int)Mm, (int)Nn, (int)Kk);
    }
}